// Round 3
// baseline (1468.445 us; speedup 1.0000x reference)
//
#include <hip/hip_runtime.h>
#include <hip/hip_fp16.h>

#define CIN   64
#define COUT  128
#define HW    56
#define LTAPS 576   // CIN * 9

// ---------------------------------------------------------------------------
// Kernel 1: build G[l][a][co] = (half) lut[a][ weight[co][l] ]
// One thread per (l, a, co-quad); writes half4 (8 B coalesced).
// ---------------------------------------------------------------------------
__global__ __launch_bounds__(256) void build_G(const int* __restrict__ weight,
                                               const float* __restrict__ lut,
                                               uint2* __restrict__ G4) {
    int idx = blockIdx.x * 256 + threadIdx.x;   // idx = (l*256 + a)*32 + c4
    int c4 = idx & 31;
    int la = idx >> 5;
    int a  = la & 255;
    int l  = la >> 8;
    int co = c4 * 4;
    const float* lr = lut + a * 256;
    __half h0 = __float2half(lr[weight[(co + 0) * LTAPS + l]]);
    __half h1 = __float2half(lr[weight[(co + 1) * LTAPS + l]]);
    __half h2 = __float2half(lr[weight[(co + 2) * LTAPS + l]]);
    __half h3 = __float2half(lr[weight[(co + 3) * LTAPS + l]]);
    __half2 p0 = __halves2half2(h0, h1);
    __half2 p1 = __halves2half2(h2, h3);
    uint2 v;
    v.x = *(unsigned int*)&p0;
    v.y = *(unsigned int*)&p1;
    G4[idx] = v;
}

// ---------------------------------------------------------------------------
// Kernel 2: main conv via pre-gathered rows, deep-pipelined gathers.
// Block = 256 threads, one 4x4 spatial tile of one image, all 128 co.
//   q = tid & 15  -> co = 8q .. 8q+7  (one 16 B dwordx4 load per row)
//   g = tid >> 4  -> pixel g of the 16-pixel tile
// Ping-pong load arrays dA/dB (9 uint4 each) keep 9-18 gathers in flight;
// two independent fp16 accumulate chains (a*/b*) break the consume chain.
// Flush to fp32 every 8 ci (36 fp16 adds per chain).
// ---------------------------------------------------------------------------

#define LOADCI(dst, ci)                                                        \
    {                                                                          \
        const unsigned char* sc = sA + (ci) * 36 + pb;                         \
        const char* Gl = Gbase + ((size_t)((ci) * 9) << 16);                   \
        dst[0] = *(const uint4*)(Gl + (0 << 16) + ((int)sc[0]  << 8));         \
        dst[1] = *(const uint4*)(Gl + (1 << 16) + ((int)sc[1]  << 8));         \
        dst[2] = *(const uint4*)(Gl + (2 << 16) + ((int)sc[2]  << 8));         \
        dst[3] = *(const uint4*)(Gl + (3 << 16) + ((int)sc[6]  << 8));         \
        dst[4] = *(const uint4*)(Gl + (4 << 16) + ((int)sc[7]  << 8));         \
        dst[5] = *(const uint4*)(Gl + (5 << 16) + ((int)sc[8]  << 8));         \
        dst[6] = *(const uint4*)(Gl + (6 << 16) + ((int)sc[12] << 8));         \
        dst[7] = *(const uint4*)(Gl + (7 << 16) + ((int)sc[13] << 8));         \
        dst[8] = *(const uint4*)(Gl + (8 << 16) + ((int)sc[14] << 8));         \
    }

#define CONSUME(src, c0, c1, c2, c3)                                           \
    {                                                                          \
        _Pragma("unroll")                                                      \
        for (int t_ = 0; t_ < 9; ++t_) {                                       \
            const __half2* h_ = (const __half2*)&src[t_];                      \
            c0 += h_[0]; c1 += h_[1]; c2 += h_[2]; c3 += h_[3];                \
        }                                                                      \
    }

__global__ __launch_bounds__(256, 4) void conv_lut(const int* __restrict__ input,
                                                   const __half* __restrict__ G,
                                                   const float* __restrict__ bias,
                                                   float* __restrict__ out) {
    __shared__ unsigned char sA[CIN * 36];   // [ci][6][6]

    int bx = blockIdx.x;
    int b  = bx / 196;          // 196 = 14*14 tiles per image
    int r  = bx % 196;
    int y0 = (r / 14) * 4;
    int x0 = (r % 14) * 4;

    int tid = threadIdx.x;

    // ---- stage 6x6 patch codes per ci (zero-pad = code 0) ----
    for (int i = tid; i < CIN * 36; i += 256) {
        int ci = i / 36, rr = i % 36;
        int yy = y0 + rr / 6 - 1;
        int xx = x0 + rr % 6 - 1;
        int v = 0;
        if (yy >= 0 && yy < HW && xx >= 0 && xx < HW)
            v = input[((b * CIN + ci) * HW + yy) * HW + xx];
        sA[i] = (unsigned char)v;
    }
    __syncthreads();

    const int q  = tid & 15;           // co octet
    const int g  = tid >> 4;           // pixel 0..15
    const int py = g >> 2, px = g & 3;
    const int pb = py * 6 + px;        // top-left of 3x3 window in 6x6 patch
    const char* Gbase = (const char*)G + q * 16;

    float accf[8] = {0.f, 0.f, 0.f, 0.f, 0.f, 0.f, 0.f, 0.f};

    uint4 dA[9], dB[9];
    LOADCI(dA, 0);

    for (int ci0 = 0; ci0 < CIN; ci0 += 8) {
        const __half2 z = __float2half2_rn(0.f);
        __half2 a0 = z, a1 = z, a2 = z, a3 = z;
        __half2 b0 = z, b1 = z, b2 = z, b3 = z;
#pragma unroll
        for (int c = 0; c < 8; c += 2) {
            const int ci = ci0 + c;
            LOADCI(dB, ci + 1);
            CONSUME(dA, a0, a1, a2, a3);
            if (ci + 2 < CIN) { LOADCI(dA, ci + 2); }
            CONSUME(dB, b0, b1, b2, b3);
        }
        a0 += b0; a1 += b1; a2 += b2; a3 += b3;
        float2 f;
        f = __half22float2(a0); accf[0] += f.x; accf[1] += f.y;
        f = __half22float2(a1); accf[2] += f.x; accf[3] += f.y;
        f = __half22float2(a2); accf[4] += f.x; accf[5] += f.y;
        f = __half22float2(a3); accf[6] += f.x; accf[7] += f.y;
    }

    // ---- epilogue: bias + store ----
    const int oh  = y0 + py, ow = x0 + px;
    const int cob = q * 8;
#pragma unroll
    for (int j = 0; j < 8; ++j) {
        const int co = cob + j;
        out[((size_t)(b * COUT + co) * HW + oh) * HW + ow] = accf[j] + bias[co];
    }
}

// ---------------------------------------------------------------------------
// Fallback (ws too small): gather lut directly, fp32 exact.
// ---------------------------------------------------------------------------
__global__ __launch_bounds__(256) void conv_direct(const int* __restrict__ input,
                                                   const int* __restrict__ weight,
                                                   const float* __restrict__ lut,
                                                   const float* __restrict__ bias,
                                                   float* __restrict__ out) {
    __shared__ unsigned char sA[CIN * 36];

    int bx = blockIdx.x;
    int b  = bx / 196;
    int r  = bx % 196;
    int y0 = (r / 14) * 4;
    int x0 = (r % 14) * 4;

    int tid = threadIdx.x;
    for (int i = tid; i < CIN * 36; i += 256) {
        int ci = i / 36, rr = i % 36;
        int yy = y0 + rr / 6 - 1;
        int xx = x0 + rr % 6 - 1;
        int v = 0;
        if (yy >= 0 && yy < HW && xx >= 0 && xx < HW)
            v = input[((b * CIN + ci) * HW + yy) * HW + xx];
        sA[i] = (unsigned char)v;
    }
    __syncthreads();

    const int q  = tid & 31;
    const int g  = tid >> 5;
    const int qv = q * 4;
    const int p0 = g * 2, p1 = p0 + 1;
    const int py0 = p0 >> 2, px0 = p0 & 3;
    const int py1 = p1 >> 2, px1 = p1 & 3;
    const int pb0 = py0 * 6 + px0;
    const int pb1 = py1 * 6 + px1;

    float acc0[4] = {0.f, 0.f, 0.f, 0.f};
    float acc1[4] = {0.f, 0.f, 0.f, 0.f};
    const int off[9] = {0, 1, 2, 6, 7, 8, 12, 13, 14};

    for (int ci = 0; ci < CIN; ++ci) {
        const int cbase = ci * 36;
#pragma unroll
        for (int t = 0; t < 9; ++t) {
            const int l = ci * 9 + t;
            const int a0 = sA[cbase + pb0 + off[t]];
            const int a1 = sA[cbase + pb1 + off[t]];
#pragma unroll
            for (int j = 0; j < 4; ++j) {
                const int w = weight[(qv + j) * LTAPS + l];
                acc0[j] += lut[a0 * 256 + w];
                acc1[j] += lut[a1 * 256 + w];
            }
        }
    }

    const int oh0 = y0 + py0, ow0 = x0 + px0;
    const int oh1 = y0 + py1, ow1 = x0 + px1;
#pragma unroll
    for (int j = 0; j < 4; ++j) {
        const int co = qv + j;
        const float bb = bias[co];
        out[((size_t)(b * COUT + co) * HW + oh0) * HW + ow0] = acc0[j] + bb;
        out[((size_t)(b * COUT + co) * HW + oh1) * HW + ow1] = acc1[j] + bb;
    }
}

// ---------------------------------------------------------------------------
extern "C" void kernel_launch(void* const* d_in, const int* in_sizes, int n_in,
                              void* d_out, int out_size, void* d_ws, size_t ws_size,
                              hipStream_t stream) {
    const int*   input  = (const int*)d_in[0];
    const int*   weight = (const int*)d_in[1];
    const float* lut    = (const float*)d_in[2];
    const float* bias   = (const float*)d_in[3];
    float*       out    = (float*)d_out;

    const size_t g_bytes = (size_t)LTAPS * 256 * 128 * sizeof(__half);  // ~37.7 MB
    const int    grid_main = 8 * 14 * 14;  // 1568 blocks

    if (ws_size >= g_bytes) {
        build_G<<<LTAPS * 32, 256, 0, stream>>>(weight, lut, (uint2*)d_ws);
        conv_lut<<<grid_main, 256, 0, stream>>>(input, (const __half*)d_ws, bias, out);
    } else {
        conv_direct<<<grid_main, 256, 0, stream>>>(input, weight, lut, bias, out);
    }
}

// Round 4
// 343.015 us; speedup vs baseline: 4.2810x; 4.2810x over previous
//
#include <hip/hip_runtime.h>
#include <hip/hip_fp16.h>

#define CIN   64
#define COUT  128
#define HW    56
#define LTAPS 576   // CIN * 9

// ---------------------------------------------------------------------------
// Kernel 1: build G[l][a][co] = (half) lut[a][ weight[co][l] ]
// One thread per (l, a, co-octet); writes half8 (16 B coalesced).
// ---------------------------------------------------------------------------
__global__ __launch_bounds__(256) void build_G(const int* __restrict__ weight,
                                               const float* __restrict__ lut,
                                               uint4* __restrict__ G8) {
    int idx = blockIdx.x * 256 + threadIdx.x;   // idx = (l*256 + a)*16 + c8
    int c8 = idx & 15;
    int la = idx >> 4;
    int a  = la & 255;
    int l  = la >> 8;
    int co = c8 * 8;
    const float* lr = lut + a * 256;
    unsigned int p[4];
#pragma unroll
    for (int j = 0; j < 4; ++j) {
        __half h0 = __float2half(lr[weight[(co + 2 * j + 0) * LTAPS + l]]);
        __half h1 = __float2half(lr[weight[(co + 2 * j + 1) * LTAPS + l]]);
        __half2 pp = __halves2half2(h0, h1);
        p[j] = *(unsigned int*)&pp;
    }
    uint4 v; v.x = p[0]; v.y = p[1]; v.z = p[2]; v.w = p[3];
    G8[idx] = v;
}

// ---------------------------------------------------------------------------
// Kernel 2: main conv via pre-gathered rows, deep-pipelined gathers.
// Block = 256 threads, one 4x4 spatial tile of one image, all 128 co.
//   q = tid & 15  -> co = 8q .. 8q+7  (one 16 B dwordx4 load per row)
//   g = tid >> 4  -> pixel g of the 16-pixel tile
// Ping-pong across 18 NAMED uint4 registers (u0..u8 / v0..v8) -> 9-18
// gathers in flight; consumption via __builtin_bit_cast (no address-taking,
// so SROA keeps everything in VGPRs -- round-3 array version spilled).
// Two independent fp16 accumulate chains, flushed to fp32 every 8 ci.
// ---------------------------------------------------------------------------

#define DECL9(p) uint4 p##0, p##1, p##2, p##3, p##4, p##5, p##6, p##7, p##8;

#define LOAD9(p, ci)                                                           \
    {                                                                          \
        const unsigned char* sc = sA + (ci) * 36 + pb;                         \
        const char* Gl = Gbase + ((size_t)((ci) * 9) << 16);                   \
        p##0 = *(const uint4*)(Gl + (0 << 16) + ((int)sc[0]  << 8));           \
        p##1 = *(const uint4*)(Gl + (1 << 16) + ((int)sc[1]  << 8));           \
        p##2 = *(const uint4*)(Gl + (2 << 16) + ((int)sc[2]  << 8));           \
        p##3 = *(const uint4*)(Gl + (3 << 16) + ((int)sc[6]  << 8));           \
        p##4 = *(const uint4*)(Gl + (4 << 16) + ((int)sc[7]  << 8));           \
        p##5 = *(const uint4*)(Gl + (5 << 16) + ((int)sc[8]  << 8));           \
        p##6 = *(const uint4*)(Gl + (6 << 16) + ((int)sc[12] << 8));           \
        p##7 = *(const uint4*)(Gl + (7 << 16) + ((int)sc[13] << 8));           \
        p##8 = *(const uint4*)(Gl + (8 << 16) + ((int)sc[14] << 8));           \
    }

#define H2C(x) __builtin_bit_cast(__half2, x)

#define ACC1(d, A0, A1, A2, A3)                                                \
    A0 += H2C(d.x); A1 += H2C(d.y); A2 += H2C(d.z); A3 += H2C(d.w);

#define ACC9(p, A0, A1, A2, A3)                                                \
    ACC1(p##0, A0, A1, A2, A3)                                                 \
    ACC1(p##1, A0, A1, A2, A3)                                                 \
    ACC1(p##2, A0, A1, A2, A3)                                                 \
    ACC1(p##3, A0, A1, A2, A3)                                                 \
    ACC1(p##4, A0, A1, A2, A3)                                                 \
    ACC1(p##5, A0, A1, A2, A3)                                                 \
    ACC1(p##6, A0, A1, A2, A3)                                                 \
    ACC1(p##7, A0, A1, A2, A3)                                                 \
    ACC1(p##8, A0, A1, A2, A3)

__global__ __launch_bounds__(256) void conv_lut(const int* __restrict__ input,
                                                const __half* __restrict__ G,
                                                const float* __restrict__ bias,
                                                float* __restrict__ out) {
    __shared__ unsigned char sA[CIN * 36];   // [ci][6][6]

    int bx = blockIdx.x;
    int b  = bx / 196;          // 196 = 14*14 tiles per image
    int r  = bx % 196;
    int y0 = (r / 14) * 4;
    int x0 = (r % 14) * 4;

    int tid = threadIdx.x;

    // ---- stage 6x6 patch codes per ci (zero-pad = code 0) ----
    for (int i = tid; i < CIN * 36; i += 256) {
        int ci = i / 36, rr = i % 36;
        int yy = y0 + rr / 6 - 1;
        int xx = x0 + rr % 6 - 1;
        int v = 0;
        if (yy >= 0 && yy < HW && xx >= 0 && xx < HW)
            v = input[((b * CIN + ci) * HW + yy) * HW + xx];
        sA[i] = (unsigned char)v;
    }
    __syncthreads();

    const int q  = tid & 15;           // co octet
    const int g  = tid >> 4;           // pixel 0..15
    const int py = g >> 2, px = g & 3;
    const int pb = py * 6 + px;        // top-left of 3x3 window in 6x6 patch
    const char* Gbase = (const char*)G + q * 16;

    float accf[8] = {0.f, 0.f, 0.f, 0.f, 0.f, 0.f, 0.f, 0.f};

    DECL9(u)
    DECL9(v)
    LOAD9(u, 0);

    for (int ci0 = 0; ci0 < CIN; ci0 += 8) {
        const __half2 z = __float2half2_rn(0.f);
        __half2 a0 = z, a1 = z, a2 = z, a3 = z;
        __half2 b0 = z, b1 = z, b2 = z, b3 = z;
#pragma unroll
        for (int c = 0; c < 8; c += 2) {
            const int ci = ci0 + c;
            LOAD9(v, ci + 1);
            ACC9(u, a0, a1, a2, a3)
            if (ci + 2 < CIN) { LOAD9(u, ci + 2); }
            ACC9(v, b0, b1, b2, b3)
        }
        a0 += b0; a1 += b1; a2 += b2; a3 += b3;
        float2 f;
        f = __half22float2(a0); accf[0] += f.x; accf[1] += f.y;
        f = __half22float2(a1); accf[2] += f.x; accf[3] += f.y;
        f = __half22float2(a2); accf[4] += f.x; accf[5] += f.y;
        f = __half22float2(a3); accf[6] += f.x; accf[7] += f.y;
    }

    // ---- epilogue: bias + store ----
    const int oh  = y0 + py, ow = x0 + px;
    const int cob = q * 8;
#pragma unroll
    for (int j = 0; j < 8; ++j) {
        const int co = cob + j;
        out[((size_t)(b * COUT + co) * HW + oh) * HW + ow] = accf[j] + bias[co];
    }
}

// ---------------------------------------------------------------------------
// Fallback (ws too small): gather lut directly, fp32 exact.
// ---------------------------------------------------------------------------
__global__ __launch_bounds__(256) void conv_direct(const int* __restrict__ input,
                                                   const int* __restrict__ weight,
                                                   const float* __restrict__ lut,
                                                   const float* __restrict__ bias,
                                                   float* __restrict__ out) {
    __shared__ unsigned char sA[CIN * 36];

    int bx = blockIdx.x;
    int b  = bx / 196;
    int r  = bx % 196;
    int y0 = (r / 14) * 4;
    int x0 = (r % 14) * 4;

    int tid = threadIdx.x;
    for (int i = tid; i < CIN * 36; i += 256) {
        int ci = i / 36, rr = i % 36;
        int yy = y0 + rr / 6 - 1;
        int xx = x0 + rr % 6 - 1;
        int v = 0;
        if (yy >= 0 && yy < HW && xx >= 0 && xx < HW)
            v = input[((b * CIN + ci) * HW + yy) * HW + xx];
        sA[i] = (unsigned char)v;
    }
    __syncthreads();

    const int q  = tid & 31;
    const int g  = tid >> 5;
    const int qv = q * 4;
    const int p0 = g * 2, p1 = p0 + 1;
    const int py0 = p0 >> 2, px0 = p0 & 3;
    const int py1 = p1 >> 2, px1 = p1 & 3;
    const int pb0 = py0 * 6 + px0;
    const int pb1 = py1 * 6 + px1;

    float acc0[4] = {0.f, 0.f, 0.f, 0.f};
    float acc1[4] = {0.f, 0.f, 0.f, 0.f};
    const int off[9] = {0, 1, 2, 6, 7, 8, 12, 13, 14};

    for (int ci = 0; ci < CIN; ++ci) {
        const int cbase = ci * 36;
#pragma unroll
        for (int t = 0; t < 9; ++t) {
            const int l = ci * 9 + t;
            const int a0 = sA[cbase + pb0 + off[t]];
            const int a1 = sA[cbase + pb1 + off[t]];
#pragma unroll
            for (int j = 0; j < 4; ++j) {
                const int w = weight[(qv + j) * LTAPS + l];
                acc0[j] += lut[a0 * 256 + w];
                acc1[j] += lut[a1 * 256 + w];
            }
        }
    }

    const int oh0 = y0 + py0, ow0 = x0 + px0;
    const int oh1 = y0 + py1, ow1 = x0 + px1;
#pragma unroll
    for (int j = 0; j < 4; ++j) {
        const int co = qv + j;
        const float bb = bias[co];
        out[((size_t)(b * COUT + co) * HW + oh0) * HW + ow0] = acc0[j] + bb;
        out[((size_t)(b * COUT + co) * HW + oh1) * HW + ow1] = acc1[j] + bb;
    }
}

// ---------------------------------------------------------------------------
extern "C" void kernel_launch(void* const* d_in, const int* in_sizes, int n_in,
                              void* d_out, int out_size, void* d_ws, size_t ws_size,
                              hipStream_t stream) {
    const int*   input  = (const int*)d_in[0];
    const int*   weight = (const int*)d_in[1];
    const float* lut    = (const float*)d_in[2];
    const float* bias   = (const float*)d_in[3];
    float*       out    = (float*)d_out;

    const size_t g_bytes = (size_t)LTAPS * 256 * 128 * sizeof(__half);  // ~37.7 MB
    const int    grid_main = 8 * 14 * 14;  // 1568 blocks

    if (ws_size >= g_bytes) {
        build_G<<<LTAPS * 16, 256, 0, stream>>>(weight, lut, (uint4*)d_ws);
        conv_lut<<<grid_main, 256, 0, stream>>>(input, (const __half*)d_ws, bias, out);
    } else {
        conv_direct<<<grid_main, 256, 0, stream>>>(input, weight, lut, bias, out);
    }
}